// Round 1
// baseline (2606.912 us; speedup 1.0000x reference)
//
#include <hip/hip_runtime.h>

#define S 3136
#define E 1024
#define H 16
#define D 64
// S/32 = 98, S/64 = 49, E/64 = 16 -- all exact, no bounds checks needed.

// C[M x N] = A[M x K] * B[N x K]^T   (row-major A, B; i.e. C = A @ B.T)
template<int N, int K>
__global__ __launch_bounds__(256) void gemm_nt(const float* __restrict__ A,
                                               const float* __restrict__ B,
                                               float* __restrict__ C) {
    __shared__ float As[16 * 68];   // As[k][m], padded stride 68 (16B-aligned rows, 2-way banks)
    __shared__ float Bs[16 * 68];   // Bs[k][n]
    const int tid = threadIdx.x;
    const int tx = tid & 15, ty = tid >> 4;
    const int m0 = blockIdx.y * 64, n0 = blockIdx.x * 64;
    float c[4][4] = {};
    for (int kt = 0; kt < K; kt += 16) {
#pragma unroll
        for (int i = 0; i < 4; ++i) {
            int e = tid + i * 256;
            int r = e >> 4, kk = e & 15;
            As[kk * 68 + r] = A[(m0 + r) * K + kt + kk];
            Bs[kk * 68 + r] = B[(n0 + r) * K + kt + kk];
        }
        __syncthreads();
#pragma unroll
        for (int kk = 0; kk < 16; ++kk) {
            const float4 a = *(const float4*)&As[kk * 68 + ty * 4];
            const float4 b = *(const float4*)&Bs[kk * 68 + tx * 4];
            float av[4] = {a.x, a.y, a.z, a.w};
            float bv[4] = {b.x, b.y, b.z, b.w};
#pragma unroll
            for (int i = 0; i < 4; ++i)
#pragma unroll
                for (int j = 0; j < 4; ++j)
                    c[i][j] += av[i] * bv[j];
        }
        __syncthreads();
    }
#pragma unroll
    for (int i = 0; i < 4; ++i) {
        float4 v = make_float4(c[i][0], c[i][1], c[i][2], c[i][3]);
        *(float4*)&C[(m0 + ty * 4 + i) * N + n0 + tx * 4] = v;
    }
}

// In-place RoPE on Q and K. rotate_half: rot[i] = -x[i+32] (i<32), x[i-32] (i>=32)
__global__ __launch_bounds__(256) void rope_kernel(float* __restrict__ Q, float* __restrict__ Kp,
                                                   const float* __restrict__ cosp,
                                                   const float* __restrict__ sinp) {
    int t = blockIdx.x * 256 + threadIdx.x;   // S*H*32 threads
    int i = t & 31;
    int h = (t >> 5) & 15;
    int s = t >> 9;
    int base = s * E + h * D;
    float c0 = cosp[s * D + i], c1 = cosp[s * D + i + 32];
    float s0 = sinp[s * D + i], s1 = sinp[s * D + i + 32];
    float q0 = Q[base + i], q1 = Q[base + i + 32];
    Q[base + i]      = q0 * c0 - q1 * s0;
    Q[base + i + 32] = q1 * c1 + q0 * s1;
    float k0 = Kp[base + i], k1 = Kp[base + i + 32];
    Kp[base + i]      = k0 * c0 - k1 * s0;
    Kp[base + i + 32] = k1 * c1 + k0 * s1;
}

// Pass A: per (head, 32 q rows): scores = (Q K^T)*0.125 -> raw into W; online (m,l) per row.
__global__ __launch_bounds__(256) void scores_pass(const float* __restrict__ Q,
                                                   const float* __restrict__ Kp,
                                                   float* __restrict__ W,
                                                   float* __restrict__ Mv,
                                                   float* __restrict__ Lv) {
    __shared__ float Qs[32 * 68];
    __shared__ float Ks[32 * 68];
    const int tid = threadIdx.x;
    const int tx = tid & 15, ty = tid >> 4;
    const int q0 = blockIdx.x * 32;
    const int h  = blockIdx.y;
#pragma unroll
    for (int i = 0; i < 8; ++i) {
        int e = tid + i * 256;
        int r = e >> 6, c = e & 63;
        Qs[r * 68 + c] = Q[(q0 + r) * E + h * D + c];
    }
    __syncthreads();
    const int qa = ty * 2;
    float m0r = -1e30f, m1r = -1e30f, l0r = 0.f, l1r = 0.f;
    const int wrow0 = h * S * S + (q0 + qa) * S;
    const int wrow1 = wrow0 + S;
    for (int kt = 0; kt < S; kt += 32) {
#pragma unroll
        for (int i = 0; i < 8; ++i) {
            int e = tid + i * 256;
            int r = e >> 6, c = e & 63;
            Ks[r * 68 + c] = Kp[(kt + r) * E + h * D + c];
        }
        __syncthreads();
        float s00 = 0, s01 = 0, s10 = 0, s11 = 0;
        const float4* q0p = (const float4*)&Qs[qa * 68];
        const float4* q1p = (const float4*)&Qs[(qa + 1) * 68];
        const float4* k0p = (const float4*)&Ks[tx * 68];
        const float4* k1p = (const float4*)&Ks[(tx + 16) * 68];
#pragma unroll
        for (int d4 = 0; d4 < 16; ++d4) {
            float4 a0 = q0p[d4], a1 = q1p[d4], b0 = k0p[d4], b1 = k1p[d4];
            s00 += a0.x * b0.x + a0.y * b0.y + a0.z * b0.z + a0.w * b0.w;
            s01 += a0.x * b1.x + a0.y * b1.y + a0.z * b1.z + a0.w * b1.w;
            s10 += a1.x * b0.x + a1.y * b0.y + a1.z * b0.z + a1.w * b0.w;
            s11 += a1.x * b1.x + a1.y * b1.y + a1.z * b1.z + a1.w * b1.w;
        }
        s00 *= 0.125f; s01 *= 0.125f; s10 *= 0.125f; s11 *= 0.125f;
        W[wrow0 + kt + tx]      = s00;
        W[wrow0 + kt + tx + 16] = s01;
        W[wrow1 + kt + tx]      = s10;
        W[wrow1 + kt + tx + 16] = s11;
        float nm0 = fmaxf(m0r, fmaxf(s00, s01));
        l0r = l0r * __expf(m0r - nm0) + __expf(s00 - nm0) + __expf(s01 - nm0);
        m0r = nm0;
        float nm1 = fmaxf(m1r, fmaxf(s10, s11));
        l1r = l1r * __expf(m1r - nm1) + __expf(s10 - nm1) + __expf(s11 - nm1);
        m1r = nm1;
        __syncthreads();
    }
    // merge (m,l) across the 16 tx lanes (same-ty lanes are contiguous in the wave)
#pragma unroll
    for (int off = 1; off < 16; off <<= 1) {
        float om = __shfl_xor(m0r, off, 64);
        float ol = __shfl_xor(l0r, off, 64);
        float nm = fmaxf(m0r, om);
        l0r = l0r * __expf(m0r - nm) + ol * __expf(om - nm);
        m0r = nm;
        om = __shfl_xor(m1r, off, 64);
        ol = __shfl_xor(l1r, off, 64);
        nm = fmaxf(m1r, om);
        l1r = l1r * __expf(m1r - nm) + ol * __expf(om - nm);
        m1r = nm;
    }
    if (tx == 0) {
        Mv[h * S + q0 + qa]     = m0r;
        Lv[h * S + q0 + qa]     = l0r;
        Mv[h * S + q0 + qa + 1] = m1r;
        Lv[h * S + q0 + qa + 1] = l1r;
    }
}

// Pass B: normalize W in place (w = exp(s-m)/l) and O = W @ V per head.
__global__ __launch_bounds__(256) void av_pass(const float* __restrict__ V,
                                               float* __restrict__ W,
                                               const float* __restrict__ Mv,
                                               const float* __restrict__ Lv,
                                               float* __restrict__ O) {
    __shared__ float Vs[32 * 64];
    __shared__ float Ss[32 * 33];
    __shared__ float sm[32], srl[32];
    const int tid = threadIdx.x;
    const int q0 = blockIdx.x * 32;
    const int h  = blockIdx.y;
    if (tid < 32) {
        sm[tid]  = Mv[h * S + q0 + tid];
        srl[tid] = 1.0f / Lv[h * S + q0 + tid];
    }
    __syncthreads();
    const int qi = tid >> 3;  // 0..31 (q row)
    const int tx = tid & 7;   // 0..7  (8 d-columns each)
    float acc[8] = {};
    const int wbase = h * S * S;
    for (int kt = 0; kt < S; kt += 32) {
#pragma unroll
        for (int i = 0; i < 8; ++i) {
            int e = tid + i * 256;
            int r = e >> 6, c = e & 63;
            Vs[r * 64 + c] = V[(kt + r) * E + h * D + c];
        }
#pragma unroll
        for (int i = 0; i < 4; ++i) {
            int e = tid + i * 256;
            int r = e >> 5, c = e & 31;
            int gi = wbase + (q0 + r) * S + kt + c;
            float s = W[gi];
            float w = __expf(s - sm[r]) * srl[r];
            W[gi] = w;
            Ss[r * 33 + c] = w;
        }
        __syncthreads();
#pragma unroll
        for (int kk = 0; kk < 32; ++kk) {
            float w = Ss[qi * 33 + kk];
            const float4* vp = (const float4*)&Vs[kk * 64 + tx * 8];
            float4 v0 = vp[0], v1 = vp[1];
            acc[0] += w * v0.x; acc[1] += w * v0.y; acc[2] += w * v0.z; acc[3] += w * v0.w;
            acc[4] += w * v1.x; acc[5] += w * v1.y; acc[6] += w * v1.z; acc[7] += w * v1.w;
        }
        __syncthreads();
    }
    float* op = &O[(q0 + qi) * E + h * D + tx * 8];
    *(float4*)op       = make_float4(acc[0], acc[1], acc[2], acc[3]);
    *((float4*)op + 1) = make_float4(acc[4], acc[5], acc[6], acc[7]);
}

extern "C" void kernel_launch(void* const* d_in, const int* in_sizes, int n_in,
                              void* d_out, int out_size, void* d_ws, size_t ws_size,
                              hipStream_t stream) {
    const float* hs   = (const float*)d_in[0];
    const float* cosp = (const float*)d_in[1];
    const float* sinp = (const float*)d_in[2];
    const float* wq   = (const float*)d_in[3];
    const float* wk   = (const float*)d_in[4];
    const float* wv   = (const float*)d_in[5];
    const float* wo   = (const float*)d_in[6];

    float* out = (float*)d_out;                 // attn_output: S*E floats
    float* W   = out + (size_t)S * E;           // attn_weights: H*S*S floats

    float* ws = (float*)d_ws;
    float* Q  = ws;                             // S*E
    float* Kp = ws + (size_t)S * E;             // S*E
    float* V  = ws + 2 * (size_t)S * E;         // S*E
    float* O  = Q;                              // reuse Q region (Q dead after scores_pass)
    float* Mv = ws + 3 * (size_t)S * E;         // H*S
    float* Lv = Mv + H * S;                     // H*S

    dim3 gproj(E / 64, S / 64);
    gemm_nt<E, E><<<gproj, 256, 0, stream>>>(hs, wq, Q);
    gemm_nt<E, E><<<gproj, 256, 0, stream>>>(hs, wk, Kp);
    gemm_nt<E, E><<<gproj, 256, 0, stream>>>(hs, wv, V);

    rope_kernel<<<(S * H * 32) / 256, 256, 0, stream>>>(Q, Kp, cosp, sinp);

    dim3 gattn(S / 32, H);
    scores_pass<<<gattn, 256, 0, stream>>>(Q, Kp, W, Mv, Lv);
    av_pass<<<gattn, 256, 0, stream>>>(V, W, Mv, Lv, O);

    gemm_nt<E, E><<<gproj, 256, 0, stream>>>(O, wo, out);
}